// Round 7
// baseline (214.524 us; speedup 1.0000x reference)
//
#include <hip/hip_runtime.h>

// mp: [1, 21, 16, 256, 256] fp32
#define CC   21
#define DD   16
#define HH   256
#define WW   256
#define HWP  (HH * WW)      // 65536
#define DHW  (DD * HWP)     // 1048576

// K_blur tile: one channel, D-half 8 (staged 12), H 4 (staged 8), W 32 (staged 40).
// A layout: h-major rows ar = py*12 + dz (py 0..7, dz 0..11), row stride 44 floats
//   (bank stride 12 -> 8 consecutive rows cover all 32 banks for b128 ops).
//   Within a row: j = (w - w0) + 4; staged j=0..39 (interior blocks) or 2..37 (edge).
// C layout: crow = y*12 + dz, stride 33 (scalar access conflict-free).
// LDS total 23.2 KB -> 6 blocks/CU (24 waves) vs round-6's 38.9 KB / 4 blocks.
#define TW 32
#define TH 4
#define DT 8
#define DPL 12               // staged d-planes
#define HPL 8                // staged h-rows
#define AROW 44
#define NR (HPL * DPL)       // 96 rows
#define A_SZ (NR * AROW)     // 4224 floats = 16.9 KB
#define CROW 33
#define CNR (TH * DPL)       // 48 rows
#define C_SZ (CNR * CROW)    // 1584 floats = 6.3 KB

__global__ __launch_bounds__(256) void blur_kernel(const float* __restrict__ mp,
                                                   float* __restrict__ out) {
    __shared__ float A[A_SZ];
    __shared__ float C[C_SZ];

    const int w0 = blockIdx.x * TW;
    const int h0 = blockIdx.y * TH;
    const int ch = blockIdx.z >> 1;
    const int dbase = (blockIdx.z & 1) * DT;
    const int tid = threadIdx.x;
    const float* __restrict__ src = mp + (size_t)ch * DHW;
    const bool edgeW = (blockIdx.x == 0) || (blockIdx.x == WW / TW - 1);

    if (!edgeW) {
        // ---- stage 96 rows x 10 float4-quads, j=0..39 <-> w = w0-4 .. w0+35 ----
#pragma unroll
        for (int k = 0; k < 4; ++k) {
            int i = tid + k * 256;
            if (i < 960) {
                int r  = i / 10;
                int q  = i - r * 10;
                int py = r / DPL, dz = r - py * DPL;
                int d = min(DD - 1, max(0, dbase + dz - 2));
                int h = min(HH - 1, max(0, h0 + py - 2));
                float4 v = *(const float4*)(src + d * HWP + h * WW + (w0 - 4 + q * 4));
                *(float4*)(&A[r * AROW + q * 4]) = v;
            }
        }
    } else {
        // ---- interior quads j=4..35 (w in-tile, no w-clamp): 768 f4 tasks ----
#pragma unroll
        for (int k = 0; k < 3; ++k) {
            int i = tid + k * 256;
            int r = i >> 3, sg = i & 7;
            int py = r / DPL, dz = r - py * DPL;
            int d = min(DD - 1, max(0, dbase + dz - 2));
            int h = min(HH - 1, max(0, h0 + py - 2));
            float4 v = *(const float4*)(src + d * HWP + h * WW + w0 + sg * 4);
            *(float4*)(&A[r * AROW + 4 + sg * 4]) = v;
        }
        // ---- w-edges j = 2,3,36,37 with clamp: 384 scalar tasks ----
#pragma unroll
        for (int k = 0; k < 2; ++k) {
            int i = tid + k * 256;
            if (i < 384) {
                int r = i >> 2, e = i & 3;
                int py = r / DPL, dz = r - py * DPL;
                int d = min(DD - 1, max(0, dbase + dz - 2));
                int h = min(HH - 1, max(0, h0 + py - 2));
                int we = (e < 2) ? (w0 + e - 2) : (w0 + 30 + e);   // w0-2,w0-1,w0+32,w0+33
                int w = min(WW - 1, max(0, we));
                int j = (e < 2) ? (2 + e) : (34 + e);              // 2,3,36,37
                A[r * AROW + j] = src[d * HWP + h * WW + w];
            }
        }
        // (j=0,1,38,39 left unstaged: read into hs[] but never used in outputs)
    }
    __syncthreads();

    // ---- WH pass: 48 crows x 4 quads = 192 tasks (crow-major lanes) ----
    if (tid < 192) {
        int crow = tid % 48;                 // y*12 + dz
        int quad = tid / 48;
        int x0   = quad * 8;
        float hs[16];
#pragma unroll
        for (int q = 0; q < 16; ++q) hs[q] = 0.f;
#pragma unroll
        for (int k = 0; k < 5; ++k) {        // H blur: ar = crow + 12k (py = y+k)
            const float* a = &A[(crow + 12 * k) * AROW + x0];
#pragma unroll
            for (int q = 0; q < 16; q += 4) {
                float4 v = *(const float4*)(a + q);
                hs[q] += v.x; hs[q + 1] += v.y; hs[q + 2] += v.z; hs[q + 3] += v.w;
            }
        }
        // W blur: out x = x0+kk needs j = x0+kk+2 .. x0+kk+6
#pragma unroll
        for (int kk = 0; kk < 8; ++kk)
            C[crow * CROW + x0 + kk] =
                hs[kk + 2] + hs[kk + 3] + hs[kk + 4] + hs[kk + 5] + hs[kk + 6];
    }
    __syncthreads();

    // ---- D pass: 4 output planes/thread, sliding window over C ----
    const int x = tid & 31, yy = (tid >> 5) & 3, dg = tid >> 7;   // dg 0..1
    float val[8];
#pragma unroll
    for (int m = 0; m < 8; ++m)
        val[m] = C[(yy * DPL + dg * 4 + m) * CROW + x];
    float* __restrict__ dst = out + (size_t)ch * DHW
                            + (size_t)(dbase + dg * 4) * HWP + (h0 + yy) * WW + w0 + x;
#pragma unroll
    for (int p = 0; p < 4; ++p)
        dst[(size_t)p * HWP] = val[p] + val[p + 1] + val[p + 2] + val[p + 3] + val[p + 4];
}

// K_med: per 4-pixel group, in place on the raw blurred values in out.
// total = sum_c blur_c. No LDS, no barriers.
__global__ __launch_bounds__(256) void median_kernel(float* __restrict__ y4) {
    const size_t i = (size_t)blockIdx.x * 256 + threadIdx.x;   // 0..262143
    const size_t base = i * 4;

    float v[CC][4];
    float tot[4] = {0.f, 0.f, 0.f, 0.f};
#pragma unroll
    for (int c = 0; c < CC; ++c) {
        float4 t = *(const float4*)(y4 + (size_t)c * DHW + base);
        v[c][0] = t.x; v[c][1] = t.y; v[c][2] = t.z; v[c][3] = t.w;
#pragma unroll
        for (int p = 0; p < 4; ++p) tot[p] += v[c][p];
    }
    float inv[4];
#pragma unroll
    for (int p = 0; p < 4; ++p) inv[p] = 1.0f / tot[p];

    float s[4] = {0.f, 0.f, 0.f, 0.f};
    float v0[4], v1[4];
    int m0[4] = {0, 0, 0, 0}, m1[4] = {0, 0, 0, 0};
#pragma unroll
    for (int c = 0; c < CC; ++c) {
#pragma unroll
        for (int p = 0; p < 4; ++p) {
            float yn = v[c][p] * inv[p];
            float sn = s[p] + yn;
            if (c == 0) { v0[p] = yn; v1[p] = yn; }                          // defaults
            if (v[c][p] > 0.f && sn < 0.5f) { m0[p] = c; v0[p] = yn; }       // last qualifying
            if (m1[p] == 0 && c > 0 && sn > 0.5f) { m1[p] = c; v1[p] = yn; } // first qualifying
            s[p] = sn;
        }
    }

#pragma unroll
    for (int c = 0; c < CC; ++c) {
        float4 o;
        o.x = (c == m0[0]) ? v0[0] : ((c == m1[0]) ? v1[0] : 0.f);
        o.y = (c == m0[1]) ? v0[1] : ((c == m1[1]) ? v1[1] : 0.f);
        o.z = (c == m0[2]) ? v0[2] : ((c == m1[2]) ? v1[2] : 0.f);
        o.w = (c == m0[3]) ? v0[3] : ((c == m1[3]) ? v1[3] : 0.f);
        *(float4*)(y4 + (size_t)c * DHW + base) = o;
    }
}

extern "C" void kernel_launch(void* const* d_in, const int* in_sizes, int n_in,
                              void* d_out, int out_size, void* d_ws, size_t ws_size,
                              hipStream_t stream) {
    const float* mp = (const float*)d_in[0];
    float* out = (float*)d_out;

    dim3 bgrid(WW / TW, HH / TH, 2 * CC);      // 8 x 64 x 42 = 21504 blocks
    blur_kernel<<<bgrid, 256, 0, stream>>>(mp, out);

    median_kernel<<<(DHW / 4) / 256, 256, 0, stream>>>(out);   // 1024 blocks
}

// Round 8
// 203.170 us; speedup vs baseline: 1.0559x; 1.0559x over previous
//
#include <hip/hip_runtime.h>

// mp: [1, 21, 16, 256, 256] fp32
#define CC   21
#define DD   16
#define HH   256
#define WW   256
#define HWP  (HH * WW)      // 65536
#define DHW  (DD * HWP)     // 1048576

// K_blur tile: one channel, full D=16, H=8 (staged 12 rows), W=32 (staged j 0..39).
// Stage phase fuses the D-blur: each task owns a (py, w-quad) column, loads 12
// d-planes as float4, computes the 5-tap sliding D-sum in registers, writes 8
// D-blurred planes to LDS. ONE barrier. WH pass reads LDS, stores to global.
// A layout: row = dout*12 + py, stride 44 (bank stride 12: 8 consecutive rows
// cover all 32 banks for b128 -> WH reads use y-minor lanes = conflict-free).
// j = (w - w0) + 4; staged j 0..39; outputs use j 2..37 only.
#define TW   32
#define TH   8
#define PYN  12              // staged h rows (h0-2 .. h0+9 clamped)
#define AROW 44
#define A_SZ (DD * PYN * AROW)   // 16*12*44 = 8448 floats = 33.8 KB -> 4 blocks/CU

__device__ __forceinline__ float4 f4add(float4 a, float4 b) {
    return make_float4(a.x + b.x, a.y + b.y, a.z + b.z, a.w + b.w);
}
__device__ __forceinline__ float4 f4sub(float4 a, float4 b) {
    return make_float4(a.x - b.x, a.y - b.y, a.z - b.z, a.w - b.w);
}

__global__ __launch_bounds__(256, 4) void blur_kernel(const float* __restrict__ mp,
                                                      float* __restrict__ out) {
    __shared__ float A[A_SZ];

    const int w0 = blockIdx.x * TW;
    const int h0 = blockIdx.y * TH;
    const int ch = blockIdx.z;
    const int tid = threadIdx.x;
    const float* __restrict__ src = mp + (size_t)ch * DHW;

    // ---- stage + D-blur: 240 tasks = 120 f4-columns (12 py x 10 jq) x 2 d-splits ----
    if (tid < 240) {
        const int s   = (tid >= 120) ? 1 : 0;      // output planes s*8 .. s*8+7
        const int col = tid - s * 120;
        const int py  = col / 10;
        const int jq  = col - py * 10;             // j = jq*4 .. jq*4+3
        const int h   = min(HH - 1, max(0, h0 + py - 2));
        int lw = w0 - 4 + jq * 4;                  // w of j=jq*4
        const bool lo = (lw < 0);                  // block.x==0, jq==0
        const bool hi = (lw > WW - 4);             // block.x==7, jq==9
        lw = lo ? 0 : (hi ? (WW - 4) : lw);
        const float* colp = src + h * WW + lw;

        float4 l[12];
#pragma unroll
        for (int m = 0; m < 12; ++m) {
            int dz = s * 8 + m;                    // staged plane index 0..19
            int d  = min(DD - 1, max(0, dz - 2));  // replicate clamp in D
            l[m] = *(const float4*)(colp + (size_t)d * HWP);
        }
        float4 sum = f4add(f4add(f4add(l[0], l[1]), f4add(l[2], l[3])), l[4]);
#pragma unroll
        for (int i = 0; i < 8; ++i) {
            float4 o = sum;
            // w-replicate fixup: lo needs j2,j3 = value at w=0 (= o.x);
            // hi needs j36,j37 = value at w=255 (= o.w). Other slots unused.
            if (lo) o = make_float4(o.x, o.x, o.x, o.x);
            if (hi) o = make_float4(o.w, o.w, o.w, o.w);
            *(float4*)(&A[((s * 8 + i) * PYN + py) * AROW + jq * 4]) = o;
            if (i < 7) sum = f4add(f4sub(sum, l[i]), l[i + 5]);
        }
    }
    __syncthreads();

    // ---- WH pass: 512 tasks (2/thread), t = dout*32 + quad*8 + y (y-minor lanes) ----
#pragma unroll
    for (int it = 0; it < 2; ++it) {
        const int t    = tid + it * 256;
        const int y    = t & 7;
        const int quad = (t >> 3) & 3;
        const int dout = t >> 5;
        const int x0   = quad * 8;

        const float* base = &A[(dout * PYN + y) * AROW + x0];
        float4 A0 = *(const float4*)(base);
        float4 A1 = *(const float4*)(base + 4);
        float4 A2 = *(const float4*)(base + 8);
        float4 A3 = *(const float4*)(base + 12);
#pragma unroll
        for (int k = 1; k < 5; ++k) {              // H blur: rows y .. y+4
            base += AROW;
            A0 = f4add(A0, *(const float4*)(base));
            A1 = f4add(A1, *(const float4*)(base + 4));
            A2 = f4add(A2, *(const float4*)(base + 8));
            A3 = f4add(A3, *(const float4*)(base + 12));
        }
        float hs[16] = {A0.x, A0.y, A0.z, A0.w, A1.x, A1.y, A1.z, A1.w,
                        A2.x, A2.y, A2.z, A2.w, A3.x, A3.y, A3.z, A3.w};
        // W blur: out x = x0+kk needs j = x0+kk+2 .. x0+kk+6 -> hs[kk+2..kk+6]
        float4 o0, o1;
        o0.x = hs[2] + hs[3] + hs[4] + hs[5] + hs[6];
        o0.y = hs[3] + hs[4] + hs[5] + hs[6] + hs[7];
        o0.z = hs[4] + hs[5] + hs[6] + hs[7] + hs[8];
        o0.w = hs[5] + hs[6] + hs[7] + hs[8] + hs[9];
        o1.x = hs[6] + hs[7] + hs[8] + hs[9] + hs[10];
        o1.y = hs[7] + hs[8] + hs[9] + hs[10] + hs[11];
        o1.z = hs[8] + hs[9] + hs[10] + hs[11] + hs[12];
        o1.w = hs[9] + hs[10] + hs[11] + hs[12] + hs[13];

        float* dst = out + (size_t)ch * DHW + (size_t)dout * HWP
                   + (h0 + y) * WW + w0 + x0;
        *(float4*)(dst)     = o0;
        *(float4*)(dst + 4) = o1;
    }
}

// K_med: per 4-pixel group, in place on the raw blurred values in out.
// total = sum_c blur_c (1/125 cancels under normalization). No LDS, no barriers.
__global__ __launch_bounds__(256) void median_kernel(float* __restrict__ y4) {
    const size_t i = (size_t)blockIdx.x * 256 + threadIdx.x;   // 0..262143
    const size_t base = i * 4;

    float v[CC][4];
    float tot[4] = {0.f, 0.f, 0.f, 0.f};
#pragma unroll
    for (int c = 0; c < CC; ++c) {
        float4 t = *(const float4*)(y4 + (size_t)c * DHW + base);
        v[c][0] = t.x; v[c][1] = t.y; v[c][2] = t.z; v[c][3] = t.w;
#pragma unroll
        for (int p = 0; p < 4; ++p) tot[p] += v[c][p];
    }
    float inv[4];
#pragma unroll
    for (int p = 0; p < 4; ++p) inv[p] = 1.0f / tot[p];

    float s[4] = {0.f, 0.f, 0.f, 0.f};
    float v0[4], v1[4];
    int m0[4] = {0, 0, 0, 0}, m1[4] = {0, 0, 0, 0};
#pragma unroll
    for (int c = 0; c < CC; ++c) {
#pragma unroll
        for (int p = 0; p < 4; ++p) {
            float yn = v[c][p] * inv[p];
            float sn = s[p] + yn;
            if (c == 0) { v0[p] = yn; v1[p] = yn; }                          // defaults
            if (v[c][p] > 0.f && sn < 0.5f) { m0[p] = c; v0[p] = yn; }       // last qualifying
            if (m1[p] == 0 && c > 0 && sn > 0.5f) { m1[p] = c; v1[p] = yn; } // first qualifying
            s[p] = sn;
        }
    }

#pragma unroll
    for (int c = 0; c < CC; ++c) {
        float4 o;
        o.x = (c == m0[0]) ? v0[0] : ((c == m1[0]) ? v1[0] : 0.f);
        o.y = (c == m0[1]) ? v0[1] : ((c == m1[1]) ? v1[1] : 0.f);
        o.z = (c == m0[2]) ? v0[2] : ((c == m1[2]) ? v1[2] : 0.f);
        o.w = (c == m0[3]) ? v0[3] : ((c == m1[3]) ? v1[3] : 0.f);
        *(float4*)(y4 + (size_t)c * DHW + base) = o;
    }
}

extern "C" void kernel_launch(void* const* d_in, const int* in_sizes, int n_in,
                              void* d_out, int out_size, void* d_ws, size_t ws_size,
                              hipStream_t stream) {
    const float* mp = (const float*)d_in[0];
    float* out = (float*)d_out;

    dim3 bgrid(WW / TW, HH / TH, CC);          // 8 x 32 x 21 = 5376 blocks
    blur_kernel<<<bgrid, 256, 0, stream>>>(mp, out);

    median_kernel<<<(DHW / 4) / 256, 256, 0, stream>>>(out);   // 1024 blocks
}

// Round 9
// 200.084 us; speedup vs baseline: 1.0722x; 1.0154x over previous
//
#include <hip/hip_runtime.h>

// mp: [1, 21, 16, 256, 256] fp32
#define CC   21
#define DD   16
#define HH   256
#define WW   256
#define HWP  (HH * WW)      // 65536
#define DHW  (DD * HWP)     // 1048576

// K_blur tile: one channel, full D=16, H=8 (staged 12 rows), W=32 (staged jj 0..35).
// jj = (w - w0) + 2  (exactly the 36 slots the WH pass consumes).
// Stage fuses the D-blur: task owns (py, jj-quad), loads 12 d-planes (8B-aligned
// vec4), sliding 5-tap D-sum in registers, writes 8 D-blurred planes to LDS.
// ONE barrier. WH pass: 3 aligned b128 reads/row (12 floats = exactly what's
// needed), H-sum over 5 rows, W-blur, float4 stores to global.
// A layout: row = plane*12 + py, stride 36 (≡4 mod 32): WH read banks =
// 16*dout + 4*(y+k) + x0 -> every 8-lane group covers all 32 banks once;
// full wave = exact 8-phase minimum, zero conflicts.
#define TW   32
#define TH   8
#define PYN  12              // staged h rows (h0-2 .. h0+9 clamped)
#define AROW 36
#define A_SZ (DD * PYN * AROW)   // 16*12*36 = 6912 floats = 27.6 KB -> 5 blocks/CU

typedef float f4u __attribute__((ext_vector_type(4), aligned(8)));

__device__ __forceinline__ f4u f4add(f4u a, f4u b) { return a + b; }

__global__ __launch_bounds__(256, 5) void blur_kernel(const float* __restrict__ mp,
                                                      float* __restrict__ out) {
    __shared__ float A[A_SZ];

    const int w0 = blockIdx.x * TW;
    const int h0 = blockIdx.y * TH;
    const int ch = blockIdx.z;
    const int tid = threadIdx.x;
    const float* __restrict__ src = mp + (size_t)ch * DHW;

    // ---- stage + D-blur: 216 tasks = 108 cols (12 py x 9 jjq) x 2 d-splits ----
    if (tid < 216) {
        const int s   = (tid >= 108) ? 1 : 0;      // output planes s*8 .. s*8+7
        const int col = tid - s * 108;
        const int py  = col / 9;
        const int jjq = col - py * 9;              // jj = jjq*4 .. jjq*4+3
        const int h   = min(HH - 1, max(0, h0 + py - 2));
        int lw = w0 - 2 + jjq * 4;                 // w of jj=jjq*4
        const bool lo = (lw < 0);                  // block.x==0, jjq==0
        const bool hi = (lw > WW - 4);             // block.x==7, jjq==8
        lw = lo ? 0 : (hi ? (WW - 4) : lw);
        const float* colp = src + h * WW + lw;

        f4u l[12];
#pragma unroll
        for (int m = 0; m < 12; ++m) {
            int dz = s * 8 + m;                    // staged plane index 0..19
            int d  = min(DD - 1, max(0, dz - 2));  // replicate clamp in D
            l[m] = *(const f4u*)(colp + (size_t)d * HWP);
        }
        f4u sum = f4add(f4add(f4add(l[0], l[1]), f4add(l[2], l[3])), l[4]);
#pragma unroll
        for (int i = 0; i < 8; ++i) {
            f4u o = sum;
            // w-replicate fixup (applied post-blur; blur is linear so it commutes):
            // lo: loaded w=[0..3] -> jj0..3 need w[-2,-1,0,1] -> (x,x,x,y)
            // hi: loaded w=[252..255] -> jj32..35 need w[254,255,255,255] -> (z,w,w,w)
            if (lo) o = f4u{o.x, o.x, o.x, o.y};
            if (hi) o = f4u{o.z, o.w, o.w, o.w};
            *(f4u*)(&A[((s * 8 + i) * PYN + py) * AROW + jjq * 4]) = o;
            if (i < 7) sum = sum - l[i] + l[i + 5];
        }
    }
    __syncthreads();

    // ---- WH pass: 512 tasks (2/thread), t = dout*32 + quad*8 + y (y-minor) ----
#pragma unroll
    for (int it = 0; it < 2; ++it) {
        const int t    = tid + it * 256;
        const int y    = t & 7;
        const int quad = (t >> 3) & 3;
        const int dout = t >> 5;
        const int x0   = quad * 8;

        // H blur over rows y..y+4; 3 aligned b128 per row (jj x0 .. x0+11)
        const float* base = &A[(dout * PYN + y) * AROW + x0];
        f4u A0 = *(const f4u*)(base);
        f4u A1 = *(const f4u*)(base + 4);
        f4u A2 = *(const f4u*)(base + 8);
#pragma unroll
        for (int k = 1; k < 5; ++k) {
            base += AROW;
            A0 = f4add(A0, *(const f4u*)(base));
            A1 = f4add(A1, *(const f4u*)(base + 4));
            A2 = f4add(A2, *(const f4u*)(base + 8));
        }
        float hs[12] = {A0.x, A0.y, A0.z, A0.w, A1.x, A1.y, A1.z, A1.w,
                        A2.x, A2.y, A2.z, A2.w};
        // W blur: out x = x0+kk needs jj = x0+kk .. x0+kk+4 -> hs[kk..kk+4]
        float4 o0, o1;
        o0.x = hs[0] + hs[1] + hs[2] + hs[3] + hs[4];
        o0.y = hs[1] + hs[2] + hs[3] + hs[4] + hs[5];
        o0.z = hs[2] + hs[3] + hs[4] + hs[5] + hs[6];
        o0.w = hs[3] + hs[4] + hs[5] + hs[6] + hs[7];
        o1.x = hs[4] + hs[5] + hs[6] + hs[7] + hs[8];
        o1.y = hs[5] + hs[6] + hs[7] + hs[8] + hs[9];
        o1.z = hs[6] + hs[7] + hs[8] + hs[9] + hs[10];
        o1.w = hs[7] + hs[8] + hs[9] + hs[10] + hs[11];

        float* dst = out + (size_t)ch * DHW + (size_t)dout * HWP
                   + (h0 + y) * WW + w0 + x0;
        *(float4*)(dst)     = o0;
        *(float4*)(dst + 4) = o1;
    }
}

// K_med: per 4-pixel group, in place on the raw blurred values in out.
// total = sum_c blur_c (1/125 cancels under normalization). No LDS, no barriers.
__global__ __launch_bounds__(256) void median_kernel(float* __restrict__ y4) {
    const size_t i = (size_t)blockIdx.x * 256 + threadIdx.x;   // 0..262143
    const size_t base = i * 4;

    float v[CC][4];
    float tot[4] = {0.f, 0.f, 0.f, 0.f};
#pragma unroll
    for (int c = 0; c < CC; ++c) {
        float4 t = *(const float4*)(y4 + (size_t)c * DHW + base);
        v[c][0] = t.x; v[c][1] = t.y; v[c][2] = t.z; v[c][3] = t.w;
#pragma unroll
        for (int p = 0; p < 4; ++p) tot[p] += v[c][p];
    }
    float inv[4];
#pragma unroll
    for (int p = 0; p < 4; ++p) inv[p] = 1.0f / tot[p];

    float s[4] = {0.f, 0.f, 0.f, 0.f};
    float v0[4], v1[4];
    int m0[4] = {0, 0, 0, 0}, m1[4] = {0, 0, 0, 0};
#pragma unroll
    for (int c = 0; c < CC; ++c) {
#pragma unroll
        for (int p = 0; p < 4; ++p) {
            float yn = v[c][p] * inv[p];
            float sn = s[p] + yn;
            if (c == 0) { v0[p] = yn; v1[p] = yn; }                          // defaults
            if (v[c][p] > 0.f && sn < 0.5f) { m0[p] = c; v0[p] = yn; }       // last qualifying
            if (m1[p] == 0 && c > 0 && sn > 0.5f) { m1[p] = c; v1[p] = yn; } // first qualifying
            s[p] = sn;
        }
    }

#pragma unroll
    for (int c = 0; c < CC; ++c) {
        float4 o;
        o.x = (c == m0[0]) ? v0[0] : ((c == m1[0]) ? v1[0] : 0.f);
        o.y = (c == m0[1]) ? v0[1] : ((c == m1[1]) ? v1[1] : 0.f);
        o.z = (c == m0[2]) ? v0[2] : ((c == m1[2]) ? v1[2] : 0.f);
        o.w = (c == m0[3]) ? v0[3] : ((c == m1[3]) ? v1[3] : 0.f);
        *(float4*)(y4 + (size_t)c * DHW + base) = o;
    }
}

extern "C" void kernel_launch(void* const* d_in, const int* in_sizes, int n_in,
                              void* d_out, int out_size, void* d_ws, size_t ws_size,
                              hipStream_t stream) {
    const float* mp = (const float*)d_in[0];
    float* out = (float*)d_out;

    dim3 bgrid(WW / TW, HH / TH, CC);          // 8 x 32 x 21 = 5376 blocks
    blur_kernel<<<bgrid, 256, 0, stream>>>(mp, out);

    median_kernel<<<(DHW / 4) / 256, 256, 0, stream>>>(out);   // 1024 blocks
}